// Round 18
// baseline (104.380 us; speedup 1.0000x reference)
//
#include <hip/hip_runtime.h>
#include <hip/hip_bf16.h>
#include <float.h>

#define DI   64
#define DOUT 62
#define CI   3
#define CO   16
#define NB   16
constexpr int SP    = DOUT * DOUT * DOUT;    // 238328
constexpr int SP64  = DOUT * DOUT * 64;      // padded per-channel y extent
constexpr int HT    = 31;                    // h-tiles of 2
constexpr int DT    = 16;                    // d-tiles of 4
constexpr int NPART = HT * DT;               // 496
constexpr int XDW   = NB * CI * DI * DI * DI / 2;   // bf16-pair dwords
constexpr int RSTR  = 33;                    // slab dword row stride (33: 4 blocks/CU)
constexpr int PHD   = 72 * RSTR;             // 2376 dwords per phase

typedef __attribute__((ext_vector_type(8))) short bf16x8;
typedef __attribute__((ext_vector_type(4))) float f32x4;

// Module BSS scratch (fully rewritten every call)
__device__ float g_psum[NB * CO * NPART];
__device__ float g_psq [NB * CO * NPART];
__device__ float g_stats[NB * CO * 2];       // (A, B') per (n,c): z = a*A + B'
__device__ uint4 g_wb4[4 * 64];              // per-lane B fragments
__device__ uint2 g_rt [4 * 64];              // per-lane row offsets (x RSTR) for gA,gB
__device__ unsigned int g_xbf[XDW];          // x as packed bf16 pairs (~25 MB)

__device__ __forceinline__ unsigned short f2bf(float v) {
    __hip_bfloat16 h = __float2bfloat16(v);
    return __builtin_bit_cast(unsigned short, h);
}
__device__ __forceinline__ unsigned int pk2(float lo, float hi) {
    return (unsigned int)f2bf(lo) | ((unsigned int)f2bf(hi) << 16);
}

// Pre-pass: x fp32 -> packed bf16 pairs; block 0 also packs weights + row table.
__global__ __launch_bounds__(256) void x2bf_kernel(const float* __restrict__ x,
                                                   const float* __restrict__ w)
{
    if (blockIdx.x == 0) {
        unsigned int* dst = (unsigned int*)g_wb4;
        for (int dwi = threadIdx.x; dwi < 4 * 64 * 4; dwi += 256) {
            const int t    = dwi >> 8;
            const int lane = (dwi >> 2) & 63;
            const int dw   = dwi & 3;
            const int o    = lane & 15, q = lane >> 4;
            const int P    = t * 4 + q;
            unsigned int u = 0;
            for (int half = 0; half < 2; ++half) {
                const int j = dw * 2 + half;
                const int g = (j < 4) ? (2 * P) : (2 * P + 1);
                const int r = j & 3;
                float val = 0.f;
                if (g <= 26 && r < 3) {
                    const int i = g / 9, kd = (g % 9) / 3, kh = g % 3;
                    val = w[o * 81 + i * 27 + kd * 9 + kh * 3 + r];
                }
                u |= ((unsigned int)f2bf(val)) << (16 * half);
            }
            dst[dwi] = u;
        }
        if (threadIdx.x < 256) {
            const int t = threadIdx.x >> 6, lane = threadIdx.x & 63;
            const int q = lane >> 4, P = t * 4 + q;
            uint2 rt;
            const int gA = 2 * P, gB = 2 * P + 1;
            rt.x = (gA <= 26) ? ((gA / 9) * 24 + ((gA % 9) / 3) * 4 + gA % 3) * RSTR : 0;
            rt.y = (gB <= 26) ? ((gB / 9) * 24 + ((gB % 9) / 3) * 4 + gB % 3) * RSTR : 0;
            g_rt[t * 64 + lane] = rt;
        }
    }
    int i = blockIdx.x * 256 + threadIdx.x;
    const int stride = gridDim.x * 256;
    for (; i < XDW / 2; i += stride) {
        const float4 v = ((const float4*)x)[i];
        uint2 u;
        u.x = pk2(v.x, v.y);
        u.y = pk2(v.z, v.w);
        ((uint2*)g_xbf)[i] = u;
    }
}

// ---------------------------------------------------------------------------
// MFMA conv. Block (64,8): wave ty -> (dl=ty>>1, hl=ty&1). Position w = 4m+wt.
// 4-phase slab (w-shifts 0..3), aligned ds_read_b64 A-gather; staging from
// g_xbf (L2/L3-warm) via uint2 + shfl + alignbit. Bias/m deferred (raw acc).
// RSTR=33 -> 39 KB LDS -> 4 blocks/CU (R16's 34 gave 3).
// MODE 0: stats only. 1: stats + y[n][ch][d][h][64] bf16. 2: recompute -> out.
// ---------------------------------------------------------------------------
template <int MODE>
__global__ __launch_bounds__(512) void conv_mfma_kernel(
    const float* __restrict__ m,
    unsigned int* __restrict__ y32, float* __restrict__ out)
{
    __shared__ unsigned int xs[4 * PHD];     // 38016 B
    __shared__ float redS[8][CO], redQ[8][CO];

    const int lane = threadIdx.x, ty = threadIdx.y;
    const int h0 = blockIdx.x * 2, d0 = blockIdx.y * 4, n = blockIdx.z;
    const int tid = ty * 64 + lane;

    // ---- stage 4 phase-interleavings (2 dword slots per iteration) ----
    for (int idx = tid; idx < 72 * 16; idx += 512) {
        const int row = idx >> 4, t = (idx & 15) * 2;
        const int i = row / 24, rm = row % 24, p = rm >> 2, hr = rm & 3;
        const int dg = min(d0 + p, DI - 1);
        const uint2 u = *(const uint2*)(g_xbf +
                          (((n * CI + i) * DI + dg) * DI + (h0 + hr)) * 32 + t);
        const unsigned D2 = __shfl_down(u.x, 1);   // next slot's lo (junk only feeds masked w>=62)
        const unsigned D3 = __shfl_down(u.y, 1);
        const unsigned a10 = __builtin_amdgcn_alignbit(u.y, u.x, 16);
        const unsigned a21 = __builtin_amdgcn_alignbit(D2, u.y, 16);
        const unsigned a32 = __builtin_amdgcn_alignbit(D3, D2, 16);
        unsigned int* dp = xs + row * RSTR + t;
        *(uint2*)(dp + 0 * PHD) = u;
        *(uint2*)(dp + 1 * PHD) = make_uint2(a10, a21);
        *(uint2*)(dp + 2 * PHD) = make_uint2(u.y, D2);
        *(uint2*)(dp + 3 * PHD) = make_uint2(a21, a32);
    }
    __syncthreads();

    const int c = lane & 15, q = lane >> 4;
    const int dl = ty >> 1, hl = ty & 1;
    const int offr = ((dl << 2) + hl) * RSTR;

    // Resident B fragments + A-gather addresses (dword units)
    bf16x8 wf[4];
    int aA[4], aB[4];
#pragma unroll
    for (int t = 0; t < 4; ++t) {
        wf[t] = __builtin_bit_cast(bf16x8, g_wb4[t * 64 + lane]);
        const uint2 rt = g_rt[t * 64 + lane];
        aA[t] = (int)rt.x + offr + 2 * c;
        aB[t] = (int)rt.y + offr + 2 * c;
    }

    const float mc = m[c];
    float A = 0.f, Bp = 0.f;
    if (MODE == 2) {
        A  = g_stats[(n * CO + c) * 2 + 0];
        Bp = g_stats[(n * CO + c) * 2 + 1];
    }

    const int d = d0 + dl, h = h0 + hl;
    const bool dvalid = d < DOUT;
    float sS = 0.f, qS = 0.f;

    if (dvalid) {
        f32x4 acc[4];
#pragma unroll
        for (int wt = 0; wt < 4; ++wt) {
            f32x4 a = {0.f, 0.f, 0.f, 0.f};
#pragma unroll
            for (int t = 0; t < 4; ++t) {
                const uint2 lo = *(const uint2*)(xs + wt * PHD + aA[t]);
                const uint2 hi = *(const uint2*)(xs + wt * PHD + aB[t]);
                uint4 av;
                av.x = lo.x; av.y = lo.y; av.z = hi.x; av.w = hi.y;
                a = __builtin_amdgcn_mfma_f32_16x16x32_bf16(
                        __builtin_bit_cast(bf16x8, av), wf[t], a, 0, 0, 0);
            }
            acc[wt] = a;
        }

        if (MODE == 2) {
            const size_t spb = (size_t)(d * DOUT + h) * DOUT + 16 * q;
#pragma unroll
            for (int reg = 0; reg < 4; ++reg)
#pragma unroll
                for (int wt = 0; wt < 4; ++wt) {
                    const int p = reg * 4 + wt;
                    float z = fminf(fmaxf(fmaf(acc[wt][reg], A, Bp), -1.f), 1.f) * mc;
                    z = fmaxf(z, __shfl_xor(z, 1));
                    z = fmaxf(z, __shfl_xor(z, 2));
                    z = fmaxf(z, __shfl_xor(z, 4));
                    z = fmaxf(z, __shfl_xor(z, 8));
                    if (c == p && (p < 14 || q < 3))
                        out[(size_t)n * SP + spb + p] = z;
                }
        } else {
            // stats on raw acc; remove invalid w=62,63 (q==3: acc[2][3], acc[3][3])
#pragma unroll
            for (int wt = 0; wt < 4; ++wt)
#pragma unroll
                for (int reg = 0; reg < 4; ++reg) {
                    const float a = acc[wt][reg];
                    sS += a; qS = fmaf(a, a, qS);
                }
            if (q == 3) {
                const float e2 = acc[2][3], e3 = acc[3][3];
                sS -= e2 + e3;
                qS -= fmaf(e2, e2, e3 * e3);
            }
            if (MODE == 1) {
                const size_t ypd = (size_t)(n * CO + c) * (SP64 / 2)
                                 + (size_t)(d * DOUT + h) * 32 + 8 * q;  // 16B-aligned
                uint4 s0, s1;
                s0.x = pk2(acc[0][0], acc[1][0]); s0.y = pk2(acc[2][0], acc[3][0]);
                s0.z = pk2(acc[0][1], acc[1][1]); s0.w = pk2(acc[2][1], acc[3][1]);
                s1.x = pk2(acc[0][2], acc[1][2]); s1.y = pk2(acc[2][2], acc[3][2]);
                s1.z = pk2(acc[0][3], acc[1][3]); s1.w = pk2(acc[2][3], acc[3][3]);
                *(uint4*)(y32 + ypd)     = s0;
                *(uint4*)(y32 + ypd + 4) = s1;    // w=62,63 land in pad, skipped by pass2
            }
        }
    }

    if (MODE != 2) {
        sS += __shfl_xor(sS, 16); qS += __shfl_xor(qS, 16);
        sS += __shfl_xor(sS, 32); qS += __shfl_xor(qS, 32);
        if (lane < 16) { redS[ty][c] = sS; redQ[ty][c] = qS; }
        __syncthreads();
        if (ty == 0 && lane < 16) {
            float s = 0.f, qq = 0.f;
#pragma unroll
            for (int wv = 0; wv < 8; ++wv) { s += redS[wv][lane]; qq += redQ[wv][lane]; }
            const int blk = blockIdx.y * HT + blockIdx.x;    // 0..495
            g_psum[(n * CO + lane) * NPART + blk] = s;
            g_psq [(n * CO + lane) * NPART + blk] = qq;
        }
    }
}

// Reduce 496 partials per (n,c) -> (A, B'):  z = a*A + B'  (b, m fold out)
__global__ __launch_bounds__(256) void finalize_stats_kernel(const float* __restrict__ m)
{
    const int idx = blockIdx.x;              // n*16 + o
    const int tid = threadIdx.x;
    __shared__ float ls[256], lq[256];
    float s = g_psum[idx * NPART + tid];
    float q = g_psq [idx * NPART + tid];
    if (tid + 256 < NPART) {
        s += g_psum[idx * NPART + tid + 256];
        q += g_psq [idx * NPART + tid + 256];
    }
    ls[tid] = s; lq[tid] = q;
    __syncthreads();
    for (int off = 128; off > 0; off >>= 1) {
        if (tid < off) { ls[tid] += ls[tid + off]; lq[tid] += lq[tid + off]; }
        __syncthreads();
    }
    if (tid == 0) {
        const float inv_n = 1.0f / (float)SP;
        const float muA = ls[0] * inv_n;
        const float varA = fmaxf(lq[0] * inv_n - muA * muA, 0.f);
        const float mo = m[idx & 15];
        const float isv = rsqrtf(fmaf(mo * mo, varA, 1e-5f));
        const float A = mo * isv;
        g_stats[idx * 2 + 0] = A;
        g_stats[idx * 2 + 1] = -muA * A;
    }
}

// Pass 2: y[n][ch][d][h][64] raw-acc bf16; 4 sp/thread via uint2 channel loads
__global__ __launch_bounds__(256) void pass2_kernel(
    const unsigned int* __restrict__ y32, const float* __restrict__ m,
    float* __restrict__ out)
{
    const int n = blockIdx.y;
    const int t2 = blockIdx.x * 256 + threadIdx.x;
    if (t2 >= DOUT * DOUT * 16) return;
    const int wp2 = t2 & 15;                 // uint2 within row -> w = 4*wp2..4*wp2+3
    const int row = t2 >> 4;                 // d*62 + h
    const float* st = g_stats + n * CO * 2;
    const uint2* yn = (const uint2*)(y32 + (size_t)n * CO * (SP64 / 2)) + t2 + row * 0;
    // dword base = row*32 + 2*wp2 -> uint2 index = row*16 + wp2 = t2
    float mx0 = -FLT_MAX, mx1 = -FLT_MAX, mx2 = -FLT_MAX, mx3 = -FLT_MAX;
#pragma unroll
    for (int o = 0; o < CO; ++o) {
        const uint2 u = yn[(size_t)o * (SP64 / 4)];
        const float A = st[o * 2], Bp = st[o * 2 + 1], mo = m[o];
        float z;
        z = fminf(fmaxf(fmaf(__uint_as_float(u.x << 16),         A, Bp), -1.f), 1.f) * mo;
        mx0 = fmaxf(mx0, z);
        z = fminf(fmaxf(fmaf(__uint_as_float(u.x & 0xFFFF0000u), A, Bp), -1.f), 1.f) * mo;
        mx1 = fmaxf(mx1, z);
        z = fminf(fmaxf(fmaf(__uint_as_float(u.y << 16),         A, Bp), -1.f), 1.f) * mo;
        mx2 = fmaxf(mx2, z);
        z = fminf(fmaxf(fmaf(__uint_as_float(u.y & 0xFFFF0000u), A, Bp), -1.f), 1.f) * mo;
        mx3 = fmaxf(mx3, z);
    }
    float* op = out + (size_t)n * SP + (size_t)row * DOUT + 4 * wp2;
    *(float2*)op = make_float2(mx0, mx1);
    if (wp2 < 15) *(float2*)(op + 2) = make_float2(mx2, mx3);   // w=62,63 skipped
}

extern "C" void kernel_launch(void* const* d_in, const int* in_sizes, int n_in,
                              void* d_out, int out_size, void* d_ws, size_t ws_size,
                              hipStream_t stream)
{
    const float* x = (const float*)d_in[0];
    const float* w = (const float*)d_in[1];
    const float* m = (const float*)d_in[3];
    float* out = (float*)d_out;

    const dim3 blk(64, 8);
    const dim3 grd(HT, DT, NB);
    const size_t yBytes = (size_t)NB * CO * SP64 * 2;   // ~126 MB

    x2bf_kernel<<<dim3(2048), dim3(256), 0, stream>>>(x, w);

    if (ws_size >= yBytes) {
        unsigned int* y = (unsigned int*)d_ws;
        conv_mfma_kernel<1><<<grd, blk, 0, stream>>>(m, y, nullptr);
        finalize_stats_kernel<<<dim3(NB * CO), dim3(256), 0, stream>>>(m);
        pass2_kernel<<<dim3((DOUT * DOUT * 16 + 255) / 256, NB), dim3(256), 0, stream>>>(y, m, out);
    } else {
        conv_mfma_kernel<0><<<grd, blk, 0, stream>>>(m, nullptr, nullptr);
        finalize_stats_kernel<<<dim3(NB * CO), dim3(256), 0, stream>>>(m);
        conv_mfma_kernel<2><<<grd, blk, 0, stream>>>(m, nullptr, out);
    }
}

// Round 19
// 91.119 us; speedup vs baseline: 1.1455x; 1.1455x over previous
//
#include <hip/hip_runtime.h>
#include <hip/hip_bf16.h>
#include <float.h>

#define DI   64
#define DOUT 62
#define CI   3
#define CO   16
#define NB   16
constexpr int SP    = DOUT * DOUT * DOUT;    // 238328
constexpr int SP64  = DOUT * DOUT * 64;      // padded per-channel y extent
constexpr int HT    = 31;                    // h-tiles of 2
constexpr int DT    = 16;                    // d-tiles of 4
constexpr int NPART = HT * DT;               // 496
constexpr int XDW   = NB * CI * DI * DI * DI / 2;   // bf16-pair dwords
constexpr int RSTR  = 34;                    // EVEN stride: keeps all b64 LDS ops 8B-aligned
                                             // (R18's 33 made odd-dword b64 -> split access, -25%)
constexpr int PHD   = 72 * RSTR;             // 2448 dwords per phase

typedef __attribute__((ext_vector_type(8))) short bf16x8;
typedef __attribute__((ext_vector_type(4))) float f32x4;

// Module BSS scratch (fully rewritten every call)
__device__ float g_psum[NB * CO * NPART];
__device__ float g_psq [NB * CO * NPART];
__device__ float g_stats[NB * CO * 2];       // (A, B') per (n,c): z = a*A + B'
__device__ uint4 g_wb4[4 * 64];              // per-lane B fragments
__device__ uint2 g_rt [4 * 64];              // per-lane row offsets (x RSTR) for gA,gB
__device__ unsigned int g_xbf[XDW];          // x as packed bf16 pairs (~25 MB)

__device__ __forceinline__ unsigned short f2bf(float v) {
    __hip_bfloat16 h = __float2bfloat16(v);
    return __builtin_bit_cast(unsigned short, h);
}
__device__ __forceinline__ unsigned int pk2(float lo, float hi) {
    return (unsigned int)f2bf(lo) | ((unsigned int)f2bf(hi) << 16);
}

// Pre-pass: x fp32 -> packed bf16 pairs; block 0 also packs weights + row table.
__global__ __launch_bounds__(256) void x2bf_kernel(const float* __restrict__ x,
                                                   const float* __restrict__ w)
{
    if (blockIdx.x == 0) {
        unsigned int* dst = (unsigned int*)g_wb4;
        for (int dwi = threadIdx.x; dwi < 4 * 64 * 4; dwi += 256) {
            const int t    = dwi >> 8;
            const int lane = (dwi >> 2) & 63;
            const int dw   = dwi & 3;
            const int o    = lane & 15, q = lane >> 4;
            const int P    = t * 4 + q;
            unsigned int u = 0;
            for (int half = 0; half < 2; ++half) {
                const int j = dw * 2 + half;
                const int g = (j < 4) ? (2 * P) : (2 * P + 1);
                const int r = j & 3;
                float val = 0.f;
                if (g <= 26 && r < 3) {
                    const int i = g / 9, kd = (g % 9) / 3, kh = g % 3;
                    val = w[o * 81 + i * 27 + kd * 9 + kh * 3 + r];
                }
                u |= ((unsigned int)f2bf(val)) << (16 * half);
            }
            dst[dwi] = u;
        }
        if (threadIdx.x < 256) {
            const int t = threadIdx.x >> 6, lane = threadIdx.x & 63;
            const int q = lane >> 4, P = t * 4 + q;
            uint2 rt;
            const int gA = 2 * P, gB = 2 * P + 1;
            rt.x = (gA <= 26) ? ((gA / 9) * 24 + ((gA % 9) / 3) * 4 + gA % 3) * RSTR : 0;
            rt.y = (gB <= 26) ? ((gB / 9) * 24 + ((gB % 9) / 3) * 4 + gB % 3) * RSTR : 0;
            g_rt[t * 64 + lane] = rt;
        }
    }
    int i = blockIdx.x * 256 + threadIdx.x;
    const int stride = gridDim.x * 256;
    for (; i < XDW / 2; i += stride) {
        const float4 v = ((const float4*)x)[i];
        uint2 u;
        u.x = pk2(v.x, v.y);
        u.y = pk2(v.z, v.w);
        ((uint2*)g_xbf)[i] = u;
    }
}

// ---------------------------------------------------------------------------
// MFMA conv. Block (64,8): wave ty -> (dl=ty>>1, hl=ty&1). Position w = 4m+wt.
// 4-phase slab (w-shifts 0..3), aligned ds_read_b64 A-gather; staging from
// g_xbf (L2/L3-warm) via uint2 + shfl + alignbit. Bias/m deferred (raw acc).
// MODE 0: stats only. 1: stats + y[n][ch][d][h][64] bf16. 2: recompute -> out.
// ---------------------------------------------------------------------------
template <int MODE>
__global__ __launch_bounds__(512) void conv_mfma_kernel(
    const float* __restrict__ m,
    unsigned int* __restrict__ y32, float* __restrict__ out)
{
    __shared__ unsigned int xs[4 * PHD];     // 39168 B
    __shared__ float redS[8][CO], redQ[8][CO];

    const int lane = threadIdx.x, ty = threadIdx.y;
    const int h0 = blockIdx.x * 2, d0 = blockIdx.y * 4, n = blockIdx.z;
    const int tid = ty * 64 + lane;

    // ---- stage 4 phase-interleavings (2 dword slots per iteration) ----
    for (int idx = tid; idx < 72 * 16; idx += 512) {
        const int row = idx >> 4, t = (idx & 15) * 2;
        const int i = row / 24, rm = row % 24, p = rm >> 2, hr = rm & 3;
        const int dg = min(d0 + p, DI - 1);
        const uint2 u = *(const uint2*)(g_xbf +
                          (((n * CI + i) * DI + dg) * DI + (h0 + hr)) * 32 + t);
        const unsigned D2 = __shfl_down(u.x, 1);   // next slot's lo (junk only feeds masked w>=62)
        const unsigned D3 = __shfl_down(u.y, 1);
        const unsigned a10 = __builtin_amdgcn_alignbit(u.y, u.x, 16);
        const unsigned a21 = __builtin_amdgcn_alignbit(D2, u.y, 16);
        const unsigned a32 = __builtin_amdgcn_alignbit(D3, D2, 16);
        unsigned int* dp = xs + row * RSTR + t;
        *(uint2*)(dp + 0 * PHD) = u;
        *(uint2*)(dp + 1 * PHD) = make_uint2(a10, a21);
        *(uint2*)(dp + 2 * PHD) = make_uint2(u.y, D2);
        *(uint2*)(dp + 3 * PHD) = make_uint2(a21, a32);
    }
    __syncthreads();

    const int c = lane & 15, q = lane >> 4;
    const int dl = ty >> 1, hl = ty & 1;
    const int offr = ((dl << 2) + hl) * RSTR;

    // Resident B fragments + A-gather addresses (dword units)
    bf16x8 wf[4];
    int aA[4], aB[4];
#pragma unroll
    for (int t = 0; t < 4; ++t) {
        wf[t] = __builtin_bit_cast(bf16x8, g_wb4[t * 64 + lane]);
        const uint2 rt = g_rt[t * 64 + lane];
        aA[t] = (int)rt.x + offr + 2 * c;
        aB[t] = (int)rt.y + offr + 2 * c;
    }

    const float mc = m[c];
    float A = 0.f, Bp = 0.f;
    if (MODE == 2) {
        A  = g_stats[(n * CO + c) * 2 + 0];
        Bp = g_stats[(n * CO + c) * 2 + 1];
    }

    const int d = d0 + dl, h = h0 + hl;
    const bool dvalid = d < DOUT;
    float sS = 0.f, qS = 0.f;

    if (dvalid) {
        f32x4 acc[4];
#pragma unroll
        for (int wt = 0; wt < 4; ++wt) {
            f32x4 a = {0.f, 0.f, 0.f, 0.f};
#pragma unroll
            for (int t = 0; t < 4; ++t) {
                const uint2 lo = *(const uint2*)(xs + wt * PHD + aA[t]);
                const uint2 hi = *(const uint2*)(xs + wt * PHD + aB[t]);
                uint4 av;
                av.x = lo.x; av.y = lo.y; av.z = hi.x; av.w = hi.y;
                a = __builtin_amdgcn_mfma_f32_16x16x32_bf16(
                        __builtin_bit_cast(bf16x8, av), wf[t], a, 0, 0, 0);
            }
            acc[wt] = a;
        }

        if (MODE == 2) {
            const size_t spb = (size_t)(d * DOUT + h) * DOUT + 16 * q;
#pragma unroll
            for (int reg = 0; reg < 4; ++reg)
#pragma unroll
                for (int wt = 0; wt < 4; ++wt) {
                    const int p = reg * 4 + wt;
                    float z = fminf(fmaxf(fmaf(acc[wt][reg], A, Bp), -1.f), 1.f) * mc;
                    z = fmaxf(z, __shfl_xor(z, 1));
                    z = fmaxf(z, __shfl_xor(z, 2));
                    z = fmaxf(z, __shfl_xor(z, 4));
                    z = fmaxf(z, __shfl_xor(z, 8));
                    if (c == p && (p < 14 || q < 3))
                        out[(size_t)n * SP + spb + p] = z;
                }
        } else {
            // stats on raw acc; remove invalid w=62,63 (q==3: acc[2][3], acc[3][3])
#pragma unroll
            for (int wt = 0; wt < 4; ++wt)
#pragma unroll
                for (int reg = 0; reg < 4; ++reg) {
                    const float a = acc[wt][reg];
                    sS += a; qS = fmaf(a, a, qS);
                }
            if (q == 3) {
                const float e2 = acc[2][3], e3 = acc[3][3];
                sS -= e2 + e3;
                qS -= fmaf(e2, e2, e3 * e3);
            }
            if (MODE == 1) {
                const size_t ypd = (size_t)(n * CO + c) * (SP64 / 2)
                                 + (size_t)(d * DOUT + h) * 32 + 8 * q;  // 16B-aligned
                uint4 s0, s1;
                s0.x = pk2(acc[0][0], acc[1][0]); s0.y = pk2(acc[2][0], acc[3][0]);
                s0.z = pk2(acc[0][1], acc[1][1]); s0.w = pk2(acc[2][1], acc[3][1]);
                s1.x = pk2(acc[0][2], acc[1][2]); s1.y = pk2(acc[2][2], acc[3][2]);
                s1.z = pk2(acc[0][3], acc[1][3]); s1.w = pk2(acc[2][3], acc[3][3]);
                *(uint4*)(y32 + ypd)     = s0;
                *(uint4*)(y32 + ypd + 4) = s1;    // w=62,63 land in pad, skipped by pass2
            }
        }
    }

    if (MODE != 2) {
        sS += __shfl_xor(sS, 16); qS += __shfl_xor(qS, 16);
        sS += __shfl_xor(sS, 32); qS += __shfl_xor(qS, 32);
        if (lane < 16) { redS[ty][c] = sS; redQ[ty][c] = qS; }
        __syncthreads();
        if (ty == 0 && lane < 16) {
            float s = 0.f, qq = 0.f;
#pragma unroll
            for (int wv = 0; wv < 8; ++wv) { s += redS[wv][lane]; qq += redQ[wv][lane]; }
            const int blk = blockIdx.y * HT + blockIdx.x;    // 0..495
            g_psum[(n * CO + lane) * NPART + blk] = s;
            g_psq [(n * CO + lane) * NPART + blk] = qq;
        }
    }
}

// Reduce 496 partials per (n,c) -> (A, B'):  z = a*A + B'  (b, m fold out)
__global__ __launch_bounds__(256) void finalize_stats_kernel(const float* __restrict__ m)
{
    const int idx = blockIdx.x;              // n*16 + o
    const int tid = threadIdx.x;
    __shared__ float ls[256], lq[256];
    float s = g_psum[idx * NPART + tid];
    float q = g_psq [idx * NPART + tid];
    if (tid + 256 < NPART) {
        s += g_psum[idx * NPART + tid + 256];
        q += g_psq [idx * NPART + tid + 256];
    }
    ls[tid] = s; lq[tid] = q;
    __syncthreads();
    for (int off = 128; off > 0; off >>= 1) {
        if (tid < off) { ls[tid] += ls[tid + off]; lq[tid] += lq[tid + off]; }
        __syncthreads();
    }
    if (tid == 0) {
        const float inv_n = 1.0f / (float)SP;
        const float muA = ls[0] * inv_n;
        const float varA = fmaxf(lq[0] * inv_n - muA * muA, 0.f);
        const float mo = m[idx & 15];
        const float isv = rsqrtf(fmaf(mo * mo, varA, 1e-5f));
        const float A = mo * isv;
        g_stats[idx * 2 + 0] = A;
        g_stats[idx * 2 + 1] = -muA * A;
    }
}

// Pass 2: y[n][ch][d][h][64] raw-acc bf16; 4 sp/thread via uint2 channel loads
__global__ __launch_bounds__(256) void pass2_kernel(
    const unsigned int* __restrict__ y32, const float* __restrict__ m,
    float* __restrict__ out)
{
    const int n = blockIdx.y;
    const int t2 = blockIdx.x * 256 + threadIdx.x;
    if (t2 >= DOUT * DOUT * 16) return;
    const int wp2 = t2 & 15;                 // uint2 within row -> w = 4*wp2..4*wp2+3
    const int row = t2 >> 4;                 // d*62 + h
    const float* st = g_stats + n * CO * 2;
    const uint2* yn = (const uint2*)(y32 + (size_t)n * CO * (SP64 / 2)) + t2;
    float mx0 = -FLT_MAX, mx1 = -FLT_MAX, mx2 = -FLT_MAX, mx3 = -FLT_MAX;
#pragma unroll
    for (int o = 0; o < CO; ++o) {
        const uint2 u = yn[(size_t)o * (SP64 / 4)];
        const float A = st[o * 2], Bp = st[o * 2 + 1], mo = m[o];
        float z;
        z = fminf(fmaxf(fmaf(__uint_as_float(u.x << 16),         A, Bp), -1.f), 1.f) * mo;
        mx0 = fmaxf(mx0, z);
        z = fminf(fmaxf(fmaf(__uint_as_float(u.x & 0xFFFF0000u), A, Bp), -1.f), 1.f) * mo;
        mx1 = fmaxf(mx1, z);
        z = fminf(fmaxf(fmaf(__uint_as_float(u.y << 16),         A, Bp), -1.f), 1.f) * mo;
        mx2 = fmaxf(mx2, z);
        z = fminf(fmaxf(fmaf(__uint_as_float(u.y & 0xFFFF0000u), A, Bp), -1.f), 1.f) * mo;
        mx3 = fmaxf(mx3, z);
    }
    float* op = out + (size_t)n * SP + (size_t)row * DOUT + 4 * wp2;
    *(float2*)op = make_float2(mx0, mx1);
    if (wp2 < 15) *(float2*)(op + 2) = make_float2(mx2, mx3);   // w=62,63 skipped
}

extern "C" void kernel_launch(void* const* d_in, const int* in_sizes, int n_in,
                              void* d_out, int out_size, void* d_ws, size_t ws_size,
                              hipStream_t stream)
{
    const float* x = (const float*)d_in[0];
    const float* w = (const float*)d_in[1];
    const float* m = (const float*)d_in[3];
    float* out = (float*)d_out;

    const dim3 blk(64, 8);
    const dim3 grd(HT, DT, NB);
    const size_t yBytes = (size_t)NB * CO * SP64 * 2;   // ~126 MB

    x2bf_kernel<<<dim3(2048), dim3(256), 0, stream>>>(x, w);

    if (ws_size >= yBytes) {
        unsigned int* y = (unsigned int*)d_ws;
        conv_mfma_kernel<1><<<grd, blk, 0, stream>>>(m, y, nullptr);
        finalize_stats_kernel<<<dim3(NB * CO), dim3(256), 0, stream>>>(m);
        pass2_kernel<<<dim3((DOUT * DOUT * 16 + 255) / 256, NB), dim3(256), 0, stream>>>(y, m, out);
    } else {
        conv_mfma_kernel<0><<<grd, blk, 0, stream>>>(m, nullptr, nullptr);
        finalize_stats_kernel<<<dim3(NB * CO), dim3(256), 0, stream>>>(m);
        conv_mfma_kernel<2><<<grd, blk, 0, stream>>>(m, nullptr, out);
    }
}

// Round 20
// 82.609 us; speedup vs baseline: 1.2635x; 1.1030x over previous
//
#include <hip/hip_runtime.h>
#include <hip/hip_bf16.h>
#include <float.h>

#define DI   64
#define DOUT 62
#define CI   3
#define CO   16
#define NB   16
constexpr int SP    = DOUT * DOUT * DOUT;    // 238328
constexpr int SP64  = DOUT * DOUT * 64;      // padded per-channel y extent
constexpr int HT    = 16;                    // h-tiles of 4
constexpr int DT    = 16;                    // d-tiles of 4
constexpr int NPART = HT * DT;               // 256
constexpr int XDW   = NB * CI * DI * DI * DI / 2;   // bf16-pair dwords
constexpr int RSTR  = 34;                    // even stride: b64 stays 8B-aligned
constexpr int ROWS  = 108;                   // 3i x 6d x 6h slab rows
constexpr int PHD2  = ROWS * RSTR;           // 3672 dwords per phase

typedef __attribute__((ext_vector_type(8))) short bf16x8;
typedef __attribute__((ext_vector_type(4))) float f32x4;

// Module BSS scratch (fully rewritten every call)
__device__ float g_psum[NB * CO * NPART];
__device__ float g_psq [NB * CO * NPART];
__device__ float g_stats[NB * CO * 2];       // (A, B') per (n,c): z = a*A + B'
__device__ uint4 g_wb4[4 * 64];              // per-lane B fragments
__device__ uint2 g_rt [4 * 64];              // per-lane row offsets (x RSTR) for gA,gB
__device__ unsigned int g_xbf[XDW];          // x as packed bf16 pairs (~25 MB)

__device__ __forceinline__ unsigned short f2bf(float v) {
    __hip_bfloat16 h = __float2bfloat16(v);
    return __builtin_bit_cast(unsigned short, h);
}
__device__ __forceinline__ unsigned int pk2(float lo, float hi) {
    return (unsigned int)f2bf(lo) | ((unsigned int)f2bf(hi) << 16);
}

// Pre-pass: x fp32 -> packed bf16 pairs; block 0 also packs weights + row table.
// baseRow(g) = i*36 + kd*6 + kh  (6x6 d,h slab grid)
__global__ __launch_bounds__(256) void x2bf_kernel(const float* __restrict__ x,
                                                   const float* __restrict__ w)
{
    if (blockIdx.x == 0) {
        unsigned int* dst = (unsigned int*)g_wb4;
        for (int dwi = threadIdx.x; dwi < 4 * 64 * 4; dwi += 256) {
            const int t    = dwi >> 8;
            const int lane = (dwi >> 2) & 63;
            const int dw   = dwi & 3;
            const int o    = lane & 15, q = lane >> 4;
            const int P    = t * 4 + q;
            unsigned int u = 0;
            for (int half = 0; half < 2; ++half) {
                const int j = dw * 2 + half;
                const int g = (j < 4) ? (2 * P) : (2 * P + 1);
                const int r = j & 3;
                float val = 0.f;
                if (g <= 26 && r < 3) {
                    const int i = g / 9, kd = (g % 9) / 3, kh = g % 3;
                    val = w[o * 81 + i * 27 + kd * 9 + kh * 3 + r];
                }
                u |= ((unsigned int)f2bf(val)) << (16 * half);
            }
            dst[dwi] = u;
        }
        if (threadIdx.x < 256) {
            const int t = threadIdx.x >> 6, lane = threadIdx.x & 63;
            const int q = lane >> 4, P = t * 4 + q;
            uint2 rt;
            const int gA = 2 * P, gB = 2 * P + 1;
            rt.x = (gA <= 26) ? ((gA / 9) * 36 + ((gA % 9) / 3) * 6 + gA % 3) * RSTR : 0;
            rt.y = (gB <= 26) ? ((gB / 9) * 36 + ((gB % 9) / 3) * 6 + gB % 3) * RSTR : 0;
            g_rt[t * 64 + lane] = rt;
        }
    }
    int i = blockIdx.x * 256 + threadIdx.x;
    const int stride = gridDim.x * 256;
    for (; i < XDW / 2; i += stride) {
        const float4 v = ((const float4*)x)[i];
        uint2 u;
        u.x = pk2(v.x, v.y);
        u.y = pk2(v.z, v.w);
        ((uint2*)g_xbf)[i] = u;
    }
}

// ---------------------------------------------------------------------------
// MFMA conv. Block (64,8) -> 4d x 4h x 62w x 16ch tile. Wave ty: dl = ty>>1
// owns depth row d0+dl; hlq = ty&1 -> TWO h-rows (hl = 2*hlq + {0,1}).
// 2-phase slab (bf16 shifts 0,1); per (row,t): 8 aligned ds_read_b64 at
// {a, a+2} x {ph0, ph1} x {A,B} serve ALL 4 wt fragments (wt2 = (d1,d2) overlap
// trick). Pad dword cols 32,33 zeroed -> m=15 over-reads finite (exact-cancel
// + zero-weight r==3 invariants). Bias/m deferred: raw-acc stats & y.
// MODE 0: stats only. 1: stats + y[n][ch][d][h][64] bf16. 2: recompute -> out.
// ---------------------------------------------------------------------------
template <int MODE>
__global__ __launch_bounds__(512) void conv_mfma_kernel(
    const float* __restrict__ m,
    unsigned int* __restrict__ y32, float* __restrict__ out)
{
    __shared__ unsigned int xs[2 * PHD2];    // 29376 B
    __shared__ float redS[8][CO], redQ[8][CO];

    const int lane = threadIdx.x, ty = threadIdx.y;
    const int h0 = blockIdx.x * 4, d0 = blockIdx.y * 4, n = blockIdx.z;
    const int tid = ty * 64 + lane;

    // zero pad cols 32,33 of every row, both phases
    for (int j = tid; j < ROWS * 2; j += 512)
        *(uint2*)(xs + (j & 1) * PHD2 + (j >> 1) * RSTR + 32) = make_uint2(0u, 0u);

    // ---- stage 2 phase-interleavings (one dword pair per item) ----
    for (int idx = tid; idx < ROWS * 16; idx += 512) {
        const int row = idx >> 4, t = (idx & 15) * 2;
        const int i = row / 36, rm = row % 36, pd = rm / 6, hr = rm % 6;
        const int dg = min(d0 + pd, DI - 1), hg = min(h0 + hr, DI - 1);
        const uint2 u = *(const uint2*)(g_xbf +
                          (((n * CI + i) * DI + dg) * DI + hg) * 32 + t);
        const unsigned D2 = __shfl_down(u.x, 1);   // next pair's lo (junk only at zero-weight/masked slots)
        unsigned int* dp = xs + row * RSTR + t;
        *(uint2*)dp = u;
        *(uint2*)(dp + PHD2) = make_uint2(__builtin_amdgcn_alignbit(u.y, u.x, 16),
                                          __builtin_amdgcn_alignbit(D2, u.y, 16));
    }
    __syncthreads();

    const int c = lane & 15, q = lane >> 4;
    const int dl = ty >> 1, hlq = ty & 1;

    // Resident B fragments + A-gather base addresses (dword units)
    bf16x8 wf[4];
    int bA[4], bB[4];
#pragma unroll
    for (int t = 0; t < 4; ++t) {
        wf[t] = __builtin_bit_cast(bf16x8, g_wb4[t * 64 + lane]);
        const uint2 rt = g_rt[t * 64 + lane];
        bA[t] = (int)rt.x + 2 * c;
        bB[t] = (int)rt.y + 2 * c;
    }

    const float mc = m[c];
    float A = 0.f, Bp = 0.f;
    if (MODE == 2) {
        A  = g_stats[(n * CO + c) * 2 + 0];
        Bp = g_stats[(n * CO + c) * 2 + 1];
    }

    const int d = d0 + dl;
    const bool dvalid = d < DOUT;
    float sS = 0.f, qS = 0.f;

#pragma unroll
    for (int r2 = 0; r2 < 2; ++r2) {
        const int hl = hlq * 2 + r2;
        const int h = h0 + hl;
        if (dvalid && h < DOUT) {
            const int offr = (dl * 6 + hl) * RSTR;
            f32x4 acc[4];
#pragma unroll
            for (int wt = 0; wt < 4; ++wt) acc[wt] = f32x4{0.f, 0.f, 0.f, 0.f};
#pragma unroll
            for (int t = 0; t < 4; ++t) {
                const int a = bA[t] + offr, b = bB[t] + offr;
                const uint2 rA0 = *(const uint2*)(xs + a);
                const uint2 rA1 = *(const uint2*)(xs + a + 2);
                const uint2 rB0 = *(const uint2*)(xs + b);
                const uint2 rB1 = *(const uint2*)(xs + b + 2);
                const uint2 sA0 = *(const uint2*)(xs + PHD2 + a);
                const uint2 sA1 = *(const uint2*)(xs + PHD2 + a + 2);
                const uint2 sB0 = *(const uint2*)(xs + PHD2 + b);
                const uint2 sB1 = *(const uint2*)(xs + PHD2 + b + 2);
                uint4 av;
                av = make_uint4(rA0.x, rA0.y, rB0.x, rB0.y);
                acc[0] = __builtin_amdgcn_mfma_f32_16x16x32_bf16(
                             __builtin_bit_cast(bf16x8, av), wf[t], acc[0], 0, 0, 0);
                av = make_uint4(sA0.x, sA0.y, sB0.x, sB0.y);
                acc[1] = __builtin_amdgcn_mfma_f32_16x16x32_bf16(
                             __builtin_bit_cast(bf16x8, av), wf[t], acc[1], 0, 0, 0);
                av = make_uint4(rA0.y, rA1.x, rB0.y, rB1.x);
                acc[2] = __builtin_amdgcn_mfma_f32_16x16x32_bf16(
                             __builtin_bit_cast(bf16x8, av), wf[t], acc[2], 0, 0, 0);
                av = make_uint4(sA0.y, sA1.x, sB0.y, sB1.x);
                acc[3] = __builtin_amdgcn_mfma_f32_16x16x32_bf16(
                             __builtin_bit_cast(bf16x8, av), wf[t], acc[3], 0, 0, 0);
            }

            if (MODE == 2) {
                const size_t spb = (size_t)(d * DOUT + h) * DOUT + 16 * q;
#pragma unroll
                for (int reg = 0; reg < 4; ++reg)
#pragma unroll
                    for (int wt = 0; wt < 4; ++wt) {
                        const int p = reg * 4 + wt;
                        float z = fminf(fmaxf(fmaf(acc[wt][reg], A, Bp), -1.f), 1.f) * mc;
                        z = fmaxf(z, __shfl_xor(z, 1));
                        z = fmaxf(z, __shfl_xor(z, 2));
                        z = fmaxf(z, __shfl_xor(z, 4));
                        z = fmaxf(z, __shfl_xor(z, 8));
                        if (c == p && (p < 14 || q < 3))
                            out[(size_t)n * SP + spb + p] = z;
                    }
            } else {
                // stats on raw acc; invalid w=62,63 (q==3: acc[2][3], acc[3][3]) cancel exactly
#pragma unroll
                for (int wt = 0; wt < 4; ++wt)
#pragma unroll
                    for (int reg = 0; reg < 4; ++reg) {
                        const float a2 = acc[wt][reg];
                        sS += a2; qS = fmaf(a2, a2, qS);
                    }
                if (q == 3) {
                    const float e2 = acc[2][3], e3 = acc[3][3];
                    sS -= e2 + e3;
                    qS -= fmaf(e2, e2, e3 * e3);
                }
                if (MODE == 1) {
                    const size_t ypd = (size_t)(n * CO + c) * (SP64 / 2)
                                     + (size_t)(d * DOUT + h) * 32 + 8 * q;  // 16B-aligned
                    uint4 s0, s1;
                    s0.x = pk2(acc[0][0], acc[1][0]); s0.y = pk2(acc[2][0], acc[3][0]);
                    s0.z = pk2(acc[0][1], acc[1][1]); s0.w = pk2(acc[2][1], acc[3][1]);
                    s1.x = pk2(acc[0][2], acc[1][2]); s1.y = pk2(acc[2][2], acc[3][2]);
                    s1.z = pk2(acc[0][3], acc[1][3]); s1.w = pk2(acc[2][3], acc[3][3]);
                    *(uint4*)(y32 + ypd)     = s0;
                    *(uint4*)(y32 + ypd + 4) = s1;    // w=62,63 land in pad, skipped by pass2
                }
            }
        }
    }

    if (MODE != 2) {
        sS += __shfl_xor(sS, 16); qS += __shfl_xor(qS, 16);
        sS += __shfl_xor(sS, 32); qS += __shfl_xor(qS, 32);
        if (lane < 16) { redS[ty][c] = sS; redQ[ty][c] = qS; }
        __syncthreads();
        if (ty == 0 && lane < 16) {
            float s = 0.f, qq = 0.f;
#pragma unroll
            for (int wv = 0; wv < 8; ++wv) { s += redS[wv][lane]; qq += redQ[wv][lane]; }
            const int blk = blockIdx.y * HT + blockIdx.x;    // 0..255
            g_psum[(n * CO + lane) * NPART + blk] = s;
            g_psq [(n * CO + lane) * NPART + blk] = qq;
        }
    }
}

// Reduce 256 partials per (n,c) -> (A, B'):  z = a*A + B'  (b, m fold out)
__global__ __launch_bounds__(256) void finalize_stats_kernel(const float* __restrict__ m)
{
    const int idx = blockIdx.x;              // n*16 + o
    const int tid = threadIdx.x;
    __shared__ float ls[256], lq[256];
    ls[tid] = g_psum[idx * NPART + tid];
    lq[tid] = g_psq [idx * NPART + tid];
    __syncthreads();
    for (int off = 128; off > 0; off >>= 1) {
        if (tid < off) { ls[tid] += ls[tid + off]; lq[tid] += lq[tid + off]; }
        __syncthreads();
    }
    if (tid == 0) {
        const float inv_n = 1.0f / (float)SP;
        const float muA = ls[0] * inv_n;
        const float varA = fmaxf(lq[0] * inv_n - muA * muA, 0.f);
        const float mo = m[idx & 15];
        const float isv = rsqrtf(fmaf(mo * mo, varA, 1e-5f));
        const float A = mo * isv;
        g_stats[idx * 2 + 0] = A;
        g_stats[idx * 2 + 1] = -muA * A;
    }
}

// Pass 2: y[n][ch][d][h][64] raw-acc bf16; 4 sp/thread via uint2 channel loads
__global__ __launch_bounds__(256) void pass2_kernel(
    const unsigned int* __restrict__ y32, const float* __restrict__ m,
    float* __restrict__ out)
{
    const int n = blockIdx.y;
    const int t2 = blockIdx.x * 256 + threadIdx.x;
    if (t2 >= DOUT * DOUT * 16) return;
    const int wp2 = t2 & 15;                 // uint2 within row -> w = 4*wp2..4*wp2+3
    const int row = t2 >> 4;                 // d*62 + h
    const float* st = g_stats + n * CO * 2;
    const uint2* yn = (const uint2*)(y32 + (size_t)n * CO * (SP64 / 2)) + t2;
    float mx0 = -FLT_MAX, mx1 = -FLT_MAX, mx2 = -FLT_MAX, mx3 = -FLT_MAX;
#pragma unroll
    for (int o = 0; o < CO; ++o) {
        const uint2 u = yn[(size_t)o * (SP64 / 4)];
        const float A = st[o * 2], Bp = st[o * 2 + 1], mo = m[o];
        float z;
        z = fminf(fmaxf(fmaf(__uint_as_float(u.x << 16),         A, Bp), -1.f), 1.f) * mo;
        mx0 = fmaxf(mx0, z);
        z = fminf(fmaxf(fmaf(__uint_as_float(u.x & 0xFFFF0000u), A, Bp), -1.f), 1.f) * mo;
        mx1 = fmaxf(mx1, z);
        z = fminf(fmaxf(fmaf(__uint_as_float(u.y << 16),         A, Bp), -1.f), 1.f) * mo;
        mx2 = fmaxf(mx2, z);
        z = fminf(fmaxf(fmaf(__uint_as_float(u.y & 0xFFFF0000u), A, Bp), -1.f), 1.f) * mo;
        mx3 = fmaxf(mx3, z);
    }
    float* op = out + (size_t)n * SP + (size_t)row * DOUT + 4 * wp2;
    *(float2*)op = make_float2(mx0, mx1);
    if (wp2 < 15) *(float2*)(op + 2) = make_float2(mx2, mx3);   // w=62,63 skipped
}

extern "C" void kernel_launch(void* const* d_in, const int* in_sizes, int n_in,
                              void* d_out, int out_size, void* d_ws, size_t ws_size,
                              hipStream_t stream)
{
    const float* x = (const float*)d_in[0];
    const float* w = (const float*)d_in[1];
    const float* m = (const float*)d_in[3];
    float* out = (float*)d_out;

    const dim3 blk(64, 8);
    const dim3 grd(HT, DT, NB);
    const size_t yBytes = (size_t)NB * CO * SP64 * 2;   // ~126 MB

    x2bf_kernel<<<dim3(2048), dim3(256), 0, stream>>>(x, w);

    if (ws_size >= yBytes) {
        unsigned int* y = (unsigned int*)d_ws;
        conv_mfma_kernel<1><<<grd, blk, 0, stream>>>(m, y, nullptr);
        finalize_stats_kernel<<<dim3(NB * CO), dim3(256), 0, stream>>>(m);
        pass2_kernel<<<dim3((DOUT * DOUT * 16 + 255) / 256, NB), dim3(256), 0, stream>>>(y, m, out);
    } else {
        conv_mfma_kernel<0><<<grd, blk, 0, stream>>>(m, nullptr, nullptr);
        finalize_stats_kernel<<<dim3(NB * CO), dim3(256), 0, stream>>>(m);
        conv_mfma_kernel<2><<<grd, blk, 0, stream>>>(m, nullptr, out);
    }
}

// Round 21
// 81.383 us; speedup vs baseline: 1.2826x; 1.0151x over previous
//
#include <hip/hip_runtime.h>
#include <hip/hip_bf16.h>
#include <float.h>

#define DI   64
#define DOUT 62
#define CI   3
#define CO   16
#define NB   16
constexpr int SP    = DOUT * DOUT * DOUT;    // 238328
constexpr int SP64  = DOUT * DOUT * 64;      // padded per-channel y extent
constexpr int HT    = 16;                    // h-tiles of 4
constexpr int DT    = 16;                    // d-tiles of 4
constexpr int NPART = HT * DT;               // 256
constexpr int XDW   = NB * CI * DI * DI * DI / 2;   // bf16-pair dwords
constexpr int RSTR  = 36;                    // 4-aligned row stride (granule swizzle)
constexpr int ROWS  = 108;                   // 3i x 6d x 6h slab rows
constexpr int PHD2  = ROWS * RSTR;           // 3888 dwords per phase

typedef __attribute__((ext_vector_type(8))) short bf16x8;
typedef __attribute__((ext_vector_type(4))) float f32x4;

// Module BSS scratch (fully rewritten every call)
__device__ float g_psum[NB * CO * NPART];
__device__ float g_psq [NB * CO * NPART];
__device__ float g_stats[NB * CO * 2];       // (A, B') per (n,c): z = a*A + B'
__device__ uint4 g_wb4[4 * 64];              // per-lane B fragments
__device__ uint2 g_rt [4 * 64];              // per-lane slab base ROWS for gA,gB
__device__ unsigned int g_xbf[XDW];          // x as packed bf16 pairs (~25 MB)

__device__ __forceinline__ unsigned short f2bf(float v) {
    __hip_bfloat16 h = __float2bfloat16(v);
    return __builtin_bit_cast(unsigned short, h);
}
__device__ __forceinline__ unsigned int pk2(float lo, float hi) {
    return (unsigned int)f2bf(lo) | ((unsigned int)f2bf(hi) << 16);
}

// Pre-pass: x fp32 -> packed bf16 pairs; block 0 also packs weights + row table.
// baseRow(g) = i*36 + kd*6 + kh  (6x6 d,h slab grid; 36 = rows per i, NOT RSTR)
__global__ __launch_bounds__(256) void x2bf_kernel(const float* __restrict__ x,
                                                   const float* __restrict__ w)
{
    if (blockIdx.x == 0) {
        unsigned int* dst = (unsigned int*)g_wb4;
        for (int dwi = threadIdx.x; dwi < 4 * 64 * 4; dwi += 256) {
            const int t    = dwi >> 8;
            const int lane = (dwi >> 2) & 63;
            const int dw   = dwi & 3;
            const int o    = lane & 15, q = lane >> 4;
            const int P    = t * 4 + q;
            unsigned int u = 0;
            for (int half = 0; half < 2; ++half) {
                const int j = dw * 2 + half;
                const int g = (j < 4) ? (2 * P) : (2 * P + 1);
                const int r = j & 3;
                float val = 0.f;
                if (g <= 26 && r < 3) {
                    const int i = g / 9, kd = (g % 9) / 3, kh = g % 3;
                    val = w[o * 81 + i * 27 + kd * 9 + kh * 3 + r];
                }
                u |= ((unsigned int)f2bf(val)) << (16 * half);
            }
            dst[dwi] = u;
        }
        if (threadIdx.x < 256) {
            const int t = threadIdx.x >> 6, lane = threadIdx.x & 63;
            const int q = lane >> 4, P = t * 4 + q;
            uint2 rt;
            const int gA = 2 * P, gB = 2 * P + 1;
            rt.x = (gA <= 26) ? (unsigned)((gA / 9) * 36 + ((gA % 9) / 3) * 6 + gA % 3) : 0u;
            rt.y = (gB <= 26) ? (unsigned)((gB / 9) * 36 + ((gB % 9) / 3) * 6 + gB % 3) : 0u;
            g_rt[t * 64 + lane] = rt;
        }
    }
    int i = blockIdx.x * 256 + threadIdx.x;
    const int stride = gridDim.x * 256;
    for (; i < XDW / 2; i += stride) {
        const float4 v = ((const float4*)x)[i];
        uint2 u;
        u.x = pk2(v.x, v.y);
        u.y = pk2(v.z, v.w);
        ((uint2*)g_xbf)[i] = u;
    }
}

// swizzled column: XOR 4-dword-granule index with (row&7); cols >=32 unswizzled
__device__ __forceinline__ int swzcol(int j, int row) {
    return (j < 32) ? (j ^ ((row & 7) << 2)) : j;
}

// ---------------------------------------------------------------------------
// MFMA conv. Block (64,8) -> 4d x 4h x 62w x 16ch tile. Wave ty: dl = ty>>1,
// hlq = ty&1 -> two h-rows. 2-phase slab, XOR-granule-swizzled columns
// (breaks the 4-q-group bank aliasing of the b64 A-gather; b64 pairs stay
// within one granule so contiguity + 8B alignment hold). Pad cols 32..35
// zeroed. Bias/m deferred: raw-acc stats & y. MODE 0: stats only.
// 1: stats + y[n][ch][d][h][64] bf16. 2: recompute -> out.
// ---------------------------------------------------------------------------
template <int MODE>
__global__ __launch_bounds__(512) void conv_mfma_kernel(
    const float* __restrict__ m,
    unsigned int* __restrict__ y32, float* __restrict__ out)
{
    __shared__ unsigned int xs[2 * PHD2];    // 31104 B
    __shared__ float redS[8][CO], redQ[8][CO];

    const int lane = threadIdx.x, ty = threadIdx.y;
    const int h0 = blockIdx.x * 4, d0 = blockIdx.y * 4, n = blockIdx.z;
    const int tid = ty * 64 + lane;

    // zero pad cols 32..35 of every row, both phases (16B aligned)
    for (int j = tid; j < ROWS * 2; j += 512)
        *(uint4*)(xs + (j & 1) * PHD2 + (j >> 1) * RSTR + 32) = make_uint4(0u, 0u, 0u, 0u);

    // ---- stage 2 phase-interleavings (one dword pair per item), swizzled cols ----
    for (int idx = tid; idx < ROWS * 16; idx += 512) {
        const int row = idx >> 4, t = (idx & 15) * 2;      // t in {0..30}
        const int i = row / 36, rm = row % 36, pd = rm / 6, hr = rm % 6;
        const int dg = min(d0 + pd, DI - 1), hg = min(h0 + hr, DI - 1);
        const uint2 u = *(const uint2*)(g_xbf +
                          (((n * CI + i) * DI + dg) * DI + hg) * 32 + t);
        const unsigned D2 = __shfl_down(u.x, 1);   // next pair's lo (junk only at zero-weight/masked slots)
        unsigned int* dp = xs + row * RSTR + (t ^ ((row & 7) << 2));
        *(uint2*)dp = u;
        *(uint2*)(dp + PHD2) = make_uint2(__builtin_amdgcn_alignbit(u.y, u.x, 16),
                                          __builtin_amdgcn_alignbit(D2, u.y, 16));
    }
    __syncthreads();

    const int c = lane & 15, q = lane >> 4;
    const int dl = ty >> 1, hlq = ty & 1;
    const int j0 = 2 * c, j1 = 2 * c + 2;

    // Resident B fragments + base slab rows
    bf16x8 wf[4];
    int rA[4], rB[4];
#pragma unroll
    for (int t = 0; t < 4; ++t) {
        wf[t] = __builtin_bit_cast(bf16x8, g_wb4[t * 64 + lane]);
        const uint2 rt = g_rt[t * 64 + lane];
        rA[t] = (int)rt.x;
        rB[t] = (int)rt.y;
    }

    const float mc = m[c];
    float A = 0.f, Bp = 0.f;
    if (MODE == 2) {
        A  = g_stats[(n * CO + c) * 2 + 0];
        Bp = g_stats[(n * CO + c) * 2 + 1];
    }

    const int d = d0 + dl;
    const bool dvalid = d < DOUT;
    float sS = 0.f, qS = 0.f;

#pragma unroll
    for (int r2 = 0; r2 < 2; ++r2) {
        const int hl = hlq * 2 + r2;
        const int h = h0 + hl;
        if (dvalid && h < DOUT) {
            const int off6 = dl * 6 + hl;
            f32x4 acc[4];
#pragma unroll
            for (int wt = 0; wt < 4; ++wt) acc[wt] = f32x4{0.f, 0.f, 0.f, 0.f};
#pragma unroll
            for (int t = 0; t < 4; ++t) {
                const int rowA = rA[t] + off6, rowB = rB[t] + off6;
                const int aA0 = rowA * RSTR + swzcol(j0, rowA);
                const int aA1 = rowA * RSTR + swzcol(j1, rowA);
                const int aB0 = rowB * RSTR + swzcol(j0, rowB);
                const int aB1 = rowB * RSTR + swzcol(j1, rowB);
                const uint2 rA0 = *(const uint2*)(xs + aA0);
                const uint2 rA1 = *(const uint2*)(xs + aA1);
                const uint2 rB0 = *(const uint2*)(xs + aB0);
                const uint2 rB1 = *(const uint2*)(xs + aB1);
                const uint2 sA0 = *(const uint2*)(xs + PHD2 + aA0);
                const uint2 sA1 = *(const uint2*)(xs + PHD2 + aA1);
                const uint2 sB0 = *(const uint2*)(xs + PHD2 + aB0);
                const uint2 sB1 = *(const uint2*)(xs + PHD2 + aB1);
                uint4 av;
                av = make_uint4(rA0.x, rA0.y, rB0.x, rB0.y);
                acc[0] = __builtin_amdgcn_mfma_f32_16x16x32_bf16(
                             __builtin_bit_cast(bf16x8, av), wf[t], acc[0], 0, 0, 0);
                av = make_uint4(sA0.x, sA0.y, sB0.x, sB0.y);
                acc[1] = __builtin_amdgcn_mfma_f32_16x16x32_bf16(
                             __builtin_bit_cast(bf16x8, av), wf[t], acc[1], 0, 0, 0);
                av = make_uint4(rA0.y, rA1.x, rB0.y, rB1.x);
                acc[2] = __builtin_amdgcn_mfma_f32_16x16x32_bf16(
                             __builtin_bit_cast(bf16x8, av), wf[t], acc[2], 0, 0, 0);
                av = make_uint4(sA0.y, sA1.x, sB0.y, sB1.x);
                acc[3] = __builtin_amdgcn_mfma_f32_16x16x32_bf16(
                             __builtin_bit_cast(bf16x8, av), wf[t], acc[3], 0, 0, 0);
            }

            if (MODE == 2) {
                const size_t spb = (size_t)(d * DOUT + h) * DOUT + 16 * q;
#pragma unroll
                for (int reg = 0; reg < 4; ++reg)
#pragma unroll
                    for (int wt = 0; wt < 4; ++wt) {
                        const int p = reg * 4 + wt;
                        float z = fminf(fmaxf(fmaf(acc[wt][reg], A, Bp), -1.f), 1.f) * mc;
                        z = fmaxf(z, __shfl_xor(z, 1));
                        z = fmaxf(z, __shfl_xor(z, 2));
                        z = fmaxf(z, __shfl_xor(z, 4));
                        z = fmaxf(z, __shfl_xor(z, 8));
                        if (c == p && (p < 14 || q < 3))
                            out[(size_t)n * SP + spb + p] = z;
                    }
            } else {
                // stats on raw acc; invalid w=62,63 (q==3: acc[2][3], acc[3][3]) subtracted exactly
#pragma unroll
                for (int wt = 0; wt < 4; ++wt)
#pragma unroll
                    for (int reg = 0; reg < 4; ++reg) {
                        const float a2 = acc[wt][reg];
                        sS += a2; qS = fmaf(a2, a2, qS);
                    }
                if (q == 3) {
                    const float e2 = acc[2][3], e3 = acc[3][3];
                    sS -= e2 + e3;
                    qS -= fmaf(e2, e2, e3 * e3);
                }
                if (MODE == 1) {
                    const size_t ypd = (size_t)(n * CO + c) * (SP64 / 2)
                                     + (size_t)(d * DOUT + h) * 32 + 8 * q;  // 16B-aligned
                    uint4 s0, s1;
                    s0.x = pk2(acc[0][0], acc[1][0]); s0.y = pk2(acc[2][0], acc[3][0]);
                    s0.z = pk2(acc[0][1], acc[1][1]); s0.w = pk2(acc[2][1], acc[3][1]);
                    s1.x = pk2(acc[0][2], acc[1][2]); s1.y = pk2(acc[2][2], acc[3][2]);
                    s1.z = pk2(acc[0][3], acc[1][3]); s1.w = pk2(acc[2][3], acc[3][3]);
                    *(uint4*)(y32 + ypd)     = s0;
                    *(uint4*)(y32 + ypd + 4) = s1;    // w=62,63 land in pad, skipped by pass2
                }
            }
        }
    }

    if (MODE != 2) {
        sS += __shfl_xor(sS, 16); qS += __shfl_xor(qS, 16);
        sS += __shfl_xor(sS, 32); qS += __shfl_xor(qS, 32);
        if (lane < 16) { redS[ty][c] = sS; redQ[ty][c] = qS; }
        __syncthreads();
        if (ty == 0 && lane < 16) {
            float s = 0.f, qq = 0.f;
#pragma unroll
            for (int wv = 0; wv < 8; ++wv) { s += redS[wv][lane]; qq += redQ[wv][lane]; }
            const int blk = blockIdx.y * HT + blockIdx.x;    // 0..255
            g_psum[(n * CO + lane) * NPART + blk] = s;
            g_psq [(n * CO + lane) * NPART + blk] = qq;
        }
    }
}

// Reduce 256 partials per (n,c) -> (A, B'):  z = a*A + B'  (b, m fold out)
__global__ __launch_bounds__(256) void finalize_stats_kernel(const float* __restrict__ m)
{
    const int idx = blockIdx.x;              // n*16 + o
    const int tid = threadIdx.x;
    __shared__ float ls[256], lq[256];
    ls[tid] = g_psum[idx * NPART + tid];
    lq[tid] = g_psq [idx * NPART + tid];
    __syncthreads();
    for (int off = 128; off > 0; off >>= 1) {
        if (tid < off) { ls[tid] += ls[tid + off]; lq[tid] += lq[tid + off]; }
        __syncthreads();
    }
    if (tid == 0) {
        const float inv_n = 1.0f / (float)SP;
        const float muA = ls[0] * inv_n;
        const float varA = fmaxf(lq[0] * inv_n - muA * muA, 0.f);
        const float mo = m[idx & 15];
        const float isv = rsqrtf(fmaf(mo * mo, varA, 1e-5f));
        const float A = mo * isv;
        g_stats[idx * 2 + 0] = A;
        g_stats[idx * 2 + 1] = -muA * A;
    }
}

// Pass 2: y[n][ch][d][h][64] raw-acc bf16; 8 sp/thread via uint4 channel loads
__global__ __launch_bounds__(256) void pass2_kernel(
    const unsigned int* __restrict__ y32, const float* __restrict__ m,
    float* __restrict__ out)
{
    const int n = blockIdx.y;
    const int t4 = blockIdx.x * 256 + threadIdx.x;
    if (t4 >= DOUT * DOUT * 8) return;
    const int wp4 = t4 & 7;                  // uint4 within row -> w = 8*wp4..8*wp4+7
    const int row = t4 >> 3;                 // d*62 + h
    const float* st = g_stats + n * CO * 2;
    const uint4* yn = (const uint4*)(y32 + (size_t)n * CO * (SP64 / 2)) + t4;
    float mx[8];
#pragma unroll
    for (int k = 0; k < 8; ++k) mx[k] = -FLT_MAX;
#pragma unroll
    for (int o = 0; o < CO; ++o) {
        const uint4 u = yn[(size_t)o * (SP64 / 8)];
        const float A = st[o * 2], Bp = st[o * 2 + 1], mo = m[o];
        const unsigned uu[4] = {u.x, u.y, u.z, u.w};
#pragma unroll
        for (int k = 0; k < 4; ++k) {
            float z;
            z = fminf(fmaxf(fmaf(__uint_as_float(uu[k] << 16),         A, Bp), -1.f), 1.f) * mo;
            mx[2 * k]     = fmaxf(mx[2 * k], z);
            z = fminf(fmaxf(fmaf(__uint_as_float(uu[k] & 0xFFFF0000u), A, Bp), -1.f), 1.f) * mo;
            mx[2 * k + 1] = fmaxf(mx[2 * k + 1], z);
        }
    }
    float* op = out + (size_t)n * SP + (size_t)row * DOUT + 8 * wp4;
    *(float2*)(op + 0) = make_float2(mx[0], mx[1]);
    *(float2*)(op + 2) = make_float2(mx[2], mx[3]);
    *(float2*)(op + 4) = make_float2(mx[4], mx[5]);
    if (wp4 < 7) *(float2*)(op + 6) = make_float2(mx[6], mx[7]);   // w=62,63 skipped
}

extern "C" void kernel_launch(void* const* d_in, const int* in_sizes, int n_in,
                              void* d_out, int out_size, void* d_ws, size_t ws_size,
                              hipStream_t stream)
{
    const float* x = (const float*)d_in[0];
    const float* w = (const float*)d_in[1];
    const float* m = (const float*)d_in[3];
    float* out = (float*)d_out;

    const dim3 blk(64, 8);
    const dim3 grd(HT, DT, NB);
    const size_t yBytes = (size_t)NB * CO * SP64 * 2;   // ~126 MB

    x2bf_kernel<<<dim3(2048), dim3(256), 0, stream>>>(x, w);

    if (ws_size >= yBytes) {
        unsigned int* y = (unsigned int*)d_ws;
        conv_mfma_kernel<1><<<grd, blk, 0, stream>>>(m, y, nullptr);
        finalize_stats_kernel<<<dim3(NB * CO), dim3(256), 0, stream>>>(m);
        pass2_kernel<<<dim3((DOUT * DOUT * 8 + 255) / 256, NB), dim3(256), 0, stream>>>(y, m, out);
    } else {
        conv_mfma_kernel<0><<<grd, blk, 0, stream>>>(m, nullptr, nullptr);
        finalize_stats_kernel<<<dim3(NB * CO), dim3(256), 0, stream>>>(m);
        conv_mfma_kernel<2><<<grd, blk, 0, stream>>>(m, nullptr, out);
    }
}